// Round 1
// baseline (442.123 us; speedup 1.0000x reference)
//
#include <hip/hip_runtime.h>

#define EPS 1e-5f

typedef __bf16 bf16;
typedef bf16 bf16x8 __attribute__((ext_vector_type(8)));
typedef float f32x4 __attribute__((ext_vector_type(4)));

__device__ __forceinline__ void lds_cp16(void* lds, const void* g) {
  __builtin_amdgcn_global_load_lds(
      (const __attribute__((address_space(1))) void*)g,
      (__attribute__((address_space(3))) void*)lds, 16, 0, 0);
}

__device__ __forceinline__ f32x4 mfma_bf16(bf16x8 a, bf16x8 b, f32x4 c) {
  return __builtin_amdgcn_mfma_f32_16x16x32_bf16(a, b, c, 0, 0, 0);
}

// ---------------- zero stats (atomic accumulators) ----------------
__global__ void k_zero(float* p) { p[blockIdx.x * 256 + threadIdx.x] = 0.0f; }

// ---------------- xe = emb[x_id] * clip(x_value, .001, 1) ----------------
__global__ void k_embed(const int* __restrict__ x_id, const float* __restrict__ x_val,
                        const float* __restrict__ emb, float* __restrict__ xe) {
  int g = blockIdx.x * 256 + threadIdx.x;  // (b*64+f)
  int id = x_id[g];
  float v = fminf(fmaxf(x_val[g], 0.001f), 1.0f);
  const float4* er = (const float4*)(emb + (size_t)id * 16);
  float4* xo = (float4*)(xe + (size_t)g * 16);
#pragma unroll
  for (int j = 0; j < 4; ++j) {
    float4 e = er[j];
    e.x *= v; e.y *= v; e.z *= v; e.w *= v;
    xo[j] = e;
  }
}

// ---------------- BN stats of exp(xe) per channel f (over b,e) ----------------
__global__ void k_expstats(const float* __restrict__ xe, const float* __restrict__ g_,
                           const float* __restrict__ b_, float* __restrict__ oa,
                           float* __restrict__ ob) {
  int f = blockIdx.x;
  int t = threadIdx.x;
  int e = t & 15, bs = t >> 4;
  float s = 0.f, q = 0.f;
  for (int i = 0; i < 256; ++i) {
    float v = __expf(xe[((size_t)(i * 16 + bs) * 64 + f) * 16 + e]);
    s += v; q += v * v;
  }
  __shared__ float rs[256], rq[256];
  rs[t] = s; rq[t] = q;
  __syncthreads();
  for (int off = 128; off > 0; off >>= 1) {
    if (t < off) { rs[t] += rs[t + off]; rq[t] += rq[t + off]; }
    __syncthreads();
  }
  if (t == 0) {
    float mean = rs[0] * (1.0f / 65536.0f);
    float var = rq[0] * (1.0f / 65536.0f) - mean * mean;
    float a = g_[f] * rsqrtf(var + EPS);
    oa[f] = a;
    ob[f] = b_[f] - mean * a;
  }
}

// ---------------- kq[k,o,x] = sum_y bil[k,x,y]*Q[k,o,y] ----------------
__global__ void k_kq(const float* __restrict__ Qw, const float* __restrict__ bil,
                     float* __restrict__ kq) {
  int t = threadIdx.x;  // t = ko
  int k = t >> 5;
  float qv[16];
#pragma unroll
  for (int y = 0; y < 16; ++y) qv[y] = Qw[t * 16 + y];
  const float* bl = bil + k * 256;
#pragma unroll
  for (int x = 0; x < 16; ++x) {
    float s = 0.f;
#pragma unroll
    for (int y = 0; y < 16; ++y) s += bl[x * 16 + y] * qv[y];
    kq[t * 16 + x] = s;
  }
}

// ---------------- per-b: sc, entmax15, aw, arm ----------------
__global__ __launch_bounds__(256, 2) void k_attn(
    const float* __restrict__ xe_g, const float* __restrict__ kq_g,
    const float* __restrict__ eba, const float* __restrict__ ebb,
    const float* __restrict__ vals, bf16* __restrict__ arm) {
  __shared__ __align__(16) float s_xe[64 * 16];
  __shared__ float s_sum[16];
  __shared__ __align__(16) bf16 s_aw[256 * 72];  // [ko][f] padded
  __shared__ __align__(16) bf16 s_X[16 * 72];    // [e][f]  padded  (B-operand)
  const int t = threadIdx.x;
  const int b = blockIdx.x;

  ((float4*)s_xe)[t] = ((const float4*)(xe_g + (size_t)b * 1024))[t];
  __syncthreads();

  if (t < 16) {
    float s = 0.f;
#pragma unroll
    for (int f = 0; f < 64; ++f) s += s_xe[f * 16 + t];
    s_sum[t] = s;
  }
  {  // x_exp staging: 4 elements per thread, transposed [e][f]
    int f = t >> 2, e0 = (t & 3) * 4;
    float a = eba[f], c = ebb[f];
#pragma unroll
    for (int j = 0; j < 4; ++j) {
      float v = __expf(s_xe[f * 16 + e0 + j]) * a + c;
      s_X[(e0 + j) * 72 + f] = (bf16)v;
    }
  }
  __syncthreads();

  // ---- per-thread: ko = t ----
  float kqv[16];
  {
    const float4* g4 = (const float4*)(kq_g + t * 16);
#pragma unroll
    for (int j = 0; j < 4; ++j) {
      float4 v = g4[j];
      kqv[j * 4 + 0] = v.x; kqv[j * 4 + 1] = v.y;
      kqv[j * 4 + 2] = v.z; kqv[j * 4 + 3] = v.w;
    }
  }
  float gc = 0.f;
#pragma unroll
  for (int x = 0; x < 16; ++x) gc += s_sum[x] * kqv[x];

  float xs[64];
#pragma unroll
  for (int f = 0; f < 64; ++f) {
    const float4* xr = (const float4*)(s_xe + f * 16);
    float4 xa = xr[0], xb = xr[1], xc = xr[2], xd = xr[3];
    float a0 = xa.x * kqv[0] + xa.y * kqv[1] + xa.z * kqv[2] + xa.w * kqv[3];
    float a1 = xb.x * kqv[4] + xb.y * kqv[5] + xb.z * kqv[6] + xb.w * kqv[7];
    float a2 = xc.x * kqv[8] + xc.y * kqv[9] + xc.z * kqv[10] + xc.w * kqv[11];
    float a3 = xd.x * kqv[12] + xd.y * kqv[13] + xd.z * kqv[14] + xd.w * kqv[15];
    xs[f] = 0.5f * (((a0 + a1) + (a2 + a3)) + gc);
  }

  float mx = xs[0];
#pragma unroll
  for (int f = 1; f < 64; ++f) mx = fmaxf(mx, xs[f]);

  float tau_lo = mx - 1.0f;
  float f_lo;
  {
    float c0 = 0, c1 = 0, c2 = 0, c3 = 0;
#pragma unroll
    for (int f = 0; f < 64; f += 4) {
      float d0 = fmaxf(xs[f] - tau_lo, 0.f);
      float d1 = fmaxf(xs[f + 1] - tau_lo, 0.f);
      float d2 = fmaxf(xs[f + 2] - tau_lo, 0.f);
      float d3 = fmaxf(xs[f + 3] - tau_lo, 0.f);
      c0 += d0 * d0; c1 += d1 * d1; c2 += d2 * d2; c3 += d3 * d3;
    }
    f_lo = ((c0 + c1) + (c2 + c3)) - 1.0f;
  }
  float dm = 0.875f;  // tau_hi - tau_lo = 1 - (1/64)^0.5
#pragma unroll
  for (int it = 0; it < 12; ++it) {
    dm *= 0.5f;
    float tau_m = tau_lo + dm;
    float c0 = 0, c1 = 0, c2 = 0, c3 = 0;
#pragma unroll
    for (int f = 0; f < 64; f += 4) {
      float d0 = fmaxf(xs[f] - tau_m, 0.f);
      float d1 = fmaxf(xs[f + 1] - tau_m, 0.f);
      float d2 = fmaxf(xs[f + 2] - tau_m, 0.f);
      float d3 = fmaxf(xs[f + 3] - tau_m, 0.f);
      c0 += d0 * d0; c1 += d1 * d1; c2 += d2 * d2; c3 += d3 * d3;
    }
    float fm = ((c0 + c1) + (c2 + c3)) - 1.0f;
    tau_lo = (fm * f_lo >= 0.f) ? tau_m : tau_lo;
  }
  // exact tau on localized support: solve |S| d^2 - 2 S1 d + (Q1-1) = 0 around tau_c
  float tau_c = tau_lo + dm;
  float S1 = 0.f, Q1 = 0.f, cnt = 0.f;
#pragma unroll
  for (int f = 0; f < 64; ++f) {
    float y = xs[f] - tau_c;
    cnt += (y > 0.f) ? 1.0f : 0.0f;
    y = fmaxf(y, 0.f);
    S1 += y; Q1 += y * y;
  }
  float disc = fmaxf(S1 * S1 - cnt * (Q1 - 1.0f), 0.f);
  float tau = tau_c + (S1 - sqrtf(disc)) / cnt;
  float Z = 0.f;
#pragma unroll
  for (int f = 0; f < 64; ++f) {
    float d = fmaxf(xs[f] - tau, 0.f);
    float pv = d * d;
    xs[f] = pv;
    Z += pv;
  }
  float inv = 1.0f / Z;

  // aw[ko][f] = (p/Z) * vals[ko][f]  -> bf16 into A-operand layout
  const float4* vg = (const float4*)(vals + t * 64);
#pragma unroll
  for (int f8 = 0; f8 < 64; f8 += 8) {
    float4 v0 = vg[f8 / 4], v1 = vg[f8 / 4 + 1];
    union { bf16 h[8]; uint4 u; } pk;
    pk.h[0] = (bf16)(xs[f8 + 0] * inv * v0.x);
    pk.h[1] = (bf16)(xs[f8 + 1] * inv * v0.y);
    pk.h[2] = (bf16)(xs[f8 + 2] * inv * v0.z);
    pk.h[3] = (bf16)(xs[f8 + 3] * inv * v0.w);
    pk.h[4] = (bf16)(xs[f8 + 4] * inv * v1.x);
    pk.h[5] = (bf16)(xs[f8 + 5] * inv * v1.y);
    pk.h[6] = (bf16)(xs[f8 + 6] * inv * v1.z);
    pk.h[7] = (bf16)(xs[f8 + 7] * inv * v1.w);
    *(uint4*)(s_aw + t * 72 + f8) = pk.u;
  }
  __syncthreads();

  // arm[ko][e] = sum_f aw[ko][f] * x_exp[f][e]  via MFMA, M=256,N=16,K=64
  const int w = t >> 6, lane = t & 63;
  f32x4 acc[4];
#pragma unroll
  for (int mt = 0; mt < 4; ++mt) acc[mt] = (f32x4){0.f, 0.f, 0.f, 0.f};
#pragma unroll
  for (int ks = 0; ks < 2; ++ks) {
    bf16x8 bfrag = *(const bf16x8*)(s_X + (lane & 15) * 72 + ks * 32 + (lane >> 4) * 8);
#pragma unroll
    for (int mt = 0; mt < 4; ++mt) {
      int row = (w * 4 + mt) * 16 + (lane & 15);
      bf16x8 afrag = *(const bf16x8*)(s_aw + row * 72 + ks * 32 + (lane >> 4) * 8);
      acc[mt] = mfma_bf16(afrag, bfrag, acc[mt]);
    }
  }
  bf16* armb = arm + (size_t)b * 4096;
#pragma unroll
  for (int mt = 0; mt < 4; ++mt) {
    int ko0 = (w * 4 + mt) * 16 + (lane >> 4) * 4;
#pragma unroll
    for (int r = 0; r < 4; ++r)
      armb[(ko0 + r) * 16 + (lane & 15)] = (bf16)acc[mt][r];
  }
}

// ---------------- arm BN stats per channel ko (over b,e) ----------------
__global__ void k_armstats(const bf16* __restrict__ arm, const float* __restrict__ g_,
                           const float* __restrict__ b_, float* __restrict__ oa,
                           float* __restrict__ oc) {
  int ko = blockIdx.x;
  int t = threadIdx.x;
  int e = t & 15, bs = t >> 4;
  float s = 0.f, q = 0.f;
  for (int i = 0; i < 256; ++i) {
    float v = (float)arm[((size_t)(i * 16 + bs) * 256 + ko) * 16 + e];
    s += v; q += v * v;
  }
  __shared__ float rs[256], rq[256];
  rs[t] = s; rq[t] = q;
  __syncthreads();
  for (int off = 128; off > 0; off >>= 1) {
    if (t < off) { rs[t] += rs[t + off]; rq[t] += rq[t + off]; }
    __syncthreads();
  }
  if (t == 0) {
    float mean = rs[0] * (1.0f / 65536.0f);
    float var = rq[0] * (1.0f / 65536.0f) - mean * mean;
    float a = g_[ko] * rsqrtf(var + EPS);
    oa[ko] = a;
    oc[ko] = b_[ko] - mean * a;
  }
}

// ---------------- normalize arm in place (bf16) ----------------
__global__ void k_armnorm(bf16* arm, const float* __restrict__ a, const float* __restrict__ c) {
  size_t i = ((size_t)blockIdx.x * 256 + threadIdx.x) * 8;
  int ko = (int)((i >> 4) & 255);
  float av = a[ko], cv = c[ko];
  bf16x8 v = *(bf16x8*)(arm + i);
#pragma unroll
  for (int j = 0; j < 8; ++j) v[j] = (bf16)((float)v[j] * av + cv);
  *(bf16x8*)(arm + i) = v;
}

// ---------------- fp32 -> bf16 convert ----------------
__global__ void k_cvt(const float* __restrict__ s, bf16* __restrict__ d, int n4) {
  int stride = gridDim.x * 256;
  for (int i = blockIdx.x * 256 + threadIdx.x; i < n4; i += stride) {
    float4 v = ((const float4*)s)[i];
    union { bf16 h[4]; uint2 u; } p;
    p.h[0] = (bf16)v.x; p.h[1] = (bf16)v.y; p.h[2] = (bf16)v.z; p.h[3] = (bf16)v.w;
    *(uint2*)(d + (size_t)i * 4) = p.u;
  }
}

// ---------------- bf16 NT GEMM 128x128xBK32, + bias, + column stats ----------------
__global__ __launch_bounds__(256, 2) void gemm_bt(
    const bf16* __restrict__ A, const bf16* __restrict__ Bw,
    const float* __restrict__ bias, float* __restrict__ C,
    float* __restrict__ csum, float* __restrict__ csq, int Kd) {
  __shared__ __align__(16) bf16 sA[128 * 32];
  __shared__ __align__(16) bf16 sB[128 * 32];
  const int t = threadIdx.x;
  const int w = t >> 6, lane = t & 63;
  const int m0 = blockIdx.x * 128, n0 = blockIdx.y * 128;
  const int wr = (w >> 1) * 64, wc = (w & 1) * 64;

  f32x4 acc[4][4];
#pragma unroll
  for (int i = 0; i < 4; ++i)
#pragma unroll
    for (int j = 0; j < 4; ++j) acc[i][j] = (f32x4){0.f, 0.f, 0.f, 0.f};

  for (int kt = 0; kt < Kd; kt += 32) {
#pragma unroll
    for (int c = 0; c < 2; ++c) {
      int idx = c * 256 + t;
      int row = idx >> 2, ch = idx & 3;
      int sch = ch ^ ((row >> 1) & 3);  // XOR swizzle to break ds_read bank conflicts
      lds_cp16(sA + idx * 8, A + (size_t)(m0 + row) * Kd + kt + sch * 8);
      lds_cp16(sB + idx * 8, Bw + (size_t)(n0 + row) * Kd + kt + sch * 8);
    }
    __syncthreads();
    bf16x8 af[4], bfr[4];
#pragma unroll
    for (int mt = 0; mt < 4; ++mt) {
      int row = wr + mt * 16 + (lane & 15);
      int ch = (lane >> 4) ^ ((row >> 1) & 3);
      af[mt] = *(const bf16x8*)(sA + row * 32 + ch * 8);
    }
#pragma unroll
    for (int nt = 0; nt < 4; ++nt) {
      int row = wc + nt * 16 + (lane & 15);
      int ch = (lane >> 4) ^ ((row >> 1) & 3);
      bfr[nt] = *(const bf16x8*)(sB + row * 32 + ch * 8);
    }
#pragma unroll
    for (int mt = 0; mt < 4; ++mt)
#pragma unroll
      for (int nt = 0; nt < 4; ++nt)
        acc[mt][nt] = mfma_bf16(af[mt], bfr[nt], acc[mt][nt]);
    __syncthreads();
  }

#pragma unroll
  for (int nt = 0; nt < 4; ++nt) {
    int ncol = n0 + wc + nt * 16 + (lane & 15);
    float bv = bias[ncol];
    float s = 0.f, q = 0.f;
#pragma unroll
    for (int mt = 0; mt < 4; ++mt) {
      int mr = m0 + wr + mt * 16 + (lane >> 4) * 4;
#pragma unroll
      for (int r = 0; r < 4; ++r) {
        float v = acc[mt][nt][r] + bv;
        C[(size_t)(mr + r) * 1024 + ncol] = v;
        s += v; q += v * v;
      }
    }
    s += __shfl_xor(s, 16, 64); s += __shfl_xor(s, 32, 64);
    q += __shfl_xor(q, 16, 64); q += __shfl_xor(q, 32, 64);
    if ((lane >> 4) == 0) {
      atomicAdd(csum + ncol, s);
      atomicAdd(csq + ncol, q);
    }
  }
}

// ---------------- finalize per-column BN coefficients ----------------
__global__ void k_colfin(const float* __restrict__ s, const float* __restrict__ q,
                         const float* __restrict__ g_, const float* __restrict__ bt,
                         float* __restrict__ a, float* __restrict__ c) {
  int h = blockIdx.x * 256 + threadIdx.x;  // < 1024
  float mean = s[h] * (1.0f / 4096.0f);
  float var = q[h] * (1.0f / 4096.0f) - mean * mean;
  float av = g_[h] * rsqrtf(var + EPS);
  a[h] = av;
  c[h] = bt[h] - mean * av;
}

// ---------------- h1 = relu(bn(C1)) -> bf16 ----------------
__global__ void k_h1bf(const float* __restrict__ C1, const float* __restrict__ a,
                       const float* __restrict__ c, bf16* __restrict__ H1) {
  int i4 = blockIdx.x * 256 + threadIdx.x;  // over 1048576
  int col0 = (i4 * 4) & 1023;
  float4 v = ((const float4*)C1)[i4];
  float4 av = *(const float4*)(a + col0);
  float4 cv = *(const float4*)(c + col0);
  union { bf16 h[4]; uint2 u; } pk;
  pk.h[0] = (bf16)fmaxf(v.x * av.x + cv.x, 0.f);
  pk.h[1] = (bf16)fmaxf(v.y * av.y + cv.y, 0.f);
  pk.h[2] = (bf16)fmaxf(v.z * av.z + cv.z, 0.f);
  pk.h[3] = (bf16)fmaxf(v.w * av.w + cv.w, 0.f);
  *(uint2*)(H1 + (size_t)i4 * 4) = pk.u;
}

// ---------------- y[b] = sum_h relu(bn(C2)) * wout + bout ----------------
__global__ __launch_bounds__(256) void k_out(const float* __restrict__ C2,
                                             const float* __restrict__ a,
                                             const float* __restrict__ c,
                                             const float* __restrict__ wout,
                                             const float* __restrict__ bout,
                                             float* __restrict__ y) {
  int t = threadIdx.x;
  int w = t >> 6, lane = t & 63;
  int row = blockIdx.x * 4 + w;
  const float* cr = C2 + (size_t)row * 1024;
  float s = 0.f;
#pragma unroll
  for (int j = 0; j < 16; ++j) {
    int col = j * 64 + lane;
    float v = fmaxf(cr[col] * a[col] + c[col], 0.f);
    s += v * wout[col];
  }
#pragma unroll
  for (int off = 32; off > 0; off >>= 1) s += __shfl_xor(s, off, 64);
  if (lane == 0) y[row] = s + bout[0];
}

extern "C" void kernel_launch(void* const* d_in, const int* in_sizes, int n_in,
                              void* d_out, int out_size, void* d_ws, size_t ws_size,
                              hipStream_t stream) {
  (void)in_sizes; (void)n_in; (void)out_size; (void)ws_size;
  const int* x_id = (const int*)d_in[0];
  const float* x_value = (const float*)d_in[1];
  const float* emb = (const float*)d_in[2];
  const float* emb_g = (const float*)d_in[3];
  const float* embb = (const float*)d_in[4];
  const float* Qw = (const float*)d_in[5];
  const float* bil = (const float*)d_in[6];
  const float* vals = (const float*)d_in[7];
  const float* arm_g = (const float*)d_in[8];
  const float* arm_b = (const float*)d_in[9];
  const float* w1 = (const float*)d_in[10];
  const float* b1 = (const float*)d_in[11];
  const float* g1 = (const float*)d_in[12];
  const float* bt1 = (const float*)d_in[13];
  const float* w2 = (const float*)d_in[14];
  const float* b2 = (const float*)d_in[15];
  const float* g2 = (const float*)d_in[16];
  const float* bt2 = (const float*)d_in[17];
  const float* wout = (const float*)d_in[18];
  const float* bout = (const float*)d_in[19];

  char* w = (char*)d_ws;
  float* ws_xe = (float*)w;                 // 16 MB: xe, later C1, later C2
  float* ws_C = ws_xe;
  bf16* ws_arm = (bf16*)(w + 16777216);     // 32 MB: arm (bf16), normalized in-place -> A1
  bf16* ws_H1 = (bf16*)(w + 50331648);      // 8 MB
  bf16* ws_w1b = (bf16*)(w + 58720256);     // 8 MB
  bf16* ws_w2b = (bf16*)(w + 67108864);     // 2 MB
  float* ws_kq = (float*)(w + 69206016);    // 16 KB
  float* eb_a = (float*)(w + 69222400);
  float* eb_b = eb_a + 64;
  float* arm_a = eb_b + 64;
  float* arm_c = arm_a + 256;
  float* s1 = arm_c + 256;   // s1,q1,s2,q2 contiguous (zeroed)
  float* q1 = s1 + 1024;
  float* s2 = q1 + 1024;
  float* q2 = s2 + 1024;
  float* a1c = q2 + 1024;
  float* c1c = a1c + 1024;
  float* a2c = c1c + 1024;
  float* c2c = a2c + 1024;

  k_zero<<<16, 256, 0, stream>>>(s1);
  k_embed<<<1024, 256, 0, stream>>>(x_id, x_value, emb, ws_xe);
  k_expstats<<<64, 256, 0, stream>>>(ws_xe, emb_g, embb, eb_a, eb_b);
  k_kq<<<1, 256, 0, stream>>>(Qw, bil, ws_kq);
  k_attn<<<4096, 256, 0, stream>>>(ws_xe, ws_kq, eb_a, eb_b, vals, ws_arm);
  k_armstats<<<256, 256, 0, stream>>>(ws_arm, arm_g, arm_b, arm_a, arm_c);
  k_armnorm<<<8192, 256, 0, stream>>>(ws_arm, arm_a, arm_c);
  k_cvt<<<1024, 256, 0, stream>>>(w1, ws_w1b, 1048576);
  k_cvt<<<256, 256, 0, stream>>>(w2, ws_w2b, 262144);
  gemm_bt<<<dim3(32, 8), 256, 0, stream>>>(ws_arm, ws_w1b, b1, ws_C, s1, q1, 4096);
  k_colfin<<<4, 256, 0, stream>>>(s1, q1, g1, bt1, a1c, c1c);
  k_h1bf<<<4096, 256, 0, stream>>>(ws_C, a1c, c1c, ws_H1);
  gemm_bt<<<dim3(32, 8), 256, 0, stream>>>(ws_H1, ws_w2b, b2, ws_C, s2, q2, 1024);
  k_colfin<<<4, 256, 0, stream>>>(s2, q2, g2, bt2, a2c, c2c);
  k_out<<<1024, 256, 0, stream>>>(ws_C, a2c, c2c, wout, bout, (float*)d_out);
}

// Round 2
// 358.148 us; speedup vs baseline: 1.2345x; 1.2345x over previous
//
#include <hip/hip_runtime.h>

#define EPS 1e-5f

typedef __bf16 bf16;
typedef bf16 bf16x8 __attribute__((ext_vector_type(8)));
typedef float f32x4 __attribute__((ext_vector_type(4)));
typedef float f32x2 __attribute__((ext_vector_type(2)));

__device__ __forceinline__ void lds_cp16(void* lds, const void* g) {
  __builtin_amdgcn_global_load_lds(
      (const __attribute__((address_space(1))) void*)g,
      (__attribute__((address_space(3))) void*)lds, 16, 0, 0);
}

__device__ __forceinline__ f32x4 mfma_bf16(bf16x8 a, bf16x8 b, f32x4 c) {
  return __builtin_amdgcn_mfma_f32_16x16x32_bf16(a, b, c, 0, 0, 0);
}

// ---------------- zero stats (atomic accumulators) ----------------
__global__ void k_zero(float* p) { p[blockIdx.x * 256 + threadIdx.x] = 0.0f; }

// ---------------- xe = emb[x_id] * clip(x_value, .001, 1) ----------------
__global__ void k_embed(const int* __restrict__ x_id, const float* __restrict__ x_val,
                        const float* __restrict__ emb, float* __restrict__ xe) {
  int g = blockIdx.x * 256 + threadIdx.x;  // (b*64+f)
  int id = x_id[g];
  float v = fminf(fmaxf(x_val[g], 0.001f), 1.0f);
  const float4* er = (const float4*)(emb + (size_t)id * 16);
  float4* xo = (float4*)(xe + (size_t)g * 16);
#pragma unroll
  for (int j = 0; j < 4; ++j) {
    float4 e = er[j];
    e.x *= v; e.y *= v; e.z *= v; e.w *= v;
    xo[j] = e;
  }
}

// ---------------- exp BN stats, coalesced + atomic ----------------
// grid 256, each block covers 16 b; thread t -> f=t>>2, e=(t&3)*4..+3
__global__ void k_expstats(const float* __restrict__ xe, float* __restrict__ es,
                           float* __restrict__ eq) {
  int t = threadIdx.x;
  int b0 = blockIdx.x * 16;
  float4 s4 = {0, 0, 0, 0}, q4 = {0, 0, 0, 0};
  for (int i = 0; i < 16; ++i) {
    float4 v = ((const float4*)(xe + (size_t)(b0 + i) * 1024))[t];
    float4 e;
    e.x = __expf(v.x); e.y = __expf(v.y); e.z = __expf(v.z); e.w = __expf(v.w);
    s4.x += e.x; s4.y += e.y; s4.z += e.z; s4.w += e.w;
    q4.x += e.x * e.x; q4.y += e.y * e.y; q4.z += e.z * e.z; q4.w += e.w * e.w;
  }
  float s = (s4.x + s4.y) + (s4.z + s4.w);
  float q = (q4.x + q4.y) + (q4.z + q4.w);
  s += __shfl_xor(s, 1, 64); s += __shfl_xor(s, 2, 64);
  q += __shfl_xor(q, 1, 64); q += __shfl_xor(q, 2, 64);
  if ((t & 3) == 0) {
    int f = t >> 2;
    atomicAdd(es + f, s);
    atomicAdd(eq + f, q);
  }
}

__global__ void k_expfin(const float* __restrict__ es, const float* __restrict__ eq,
                         const float* __restrict__ g_, const float* __restrict__ b_,
                         float* __restrict__ oa, float* __restrict__ ob) {
  int f = threadIdx.x;  // 64
  float mean = es[f] * (1.0f / 65536.0f);
  float var = eq[f] * (1.0f / 65536.0f) - mean * mean;
  float a = g_[f] * rsqrtf(var + EPS);
  oa[f] = a;
  ob[f] = b_[f] - mean * a;
}

// ---------------- kq[k,o,x] = 0.5 * sum_y bil[k,x,y]*Q[k,o,y] ----------------
__global__ void k_kq(const float* __restrict__ Qw, const float* __restrict__ bil,
                     float* __restrict__ kq) {
  int t = threadIdx.x;  // t = ko
  int k = t >> 5;
  float qv[16];
#pragma unroll
  for (int y = 0; y < 16; ++y) qv[y] = Qw[t * 16 + y];
  const float* bl = bil + k * 256;
#pragma unroll
  for (int x = 0; x < 16; ++x) {
    float s = 0.f;
#pragma unroll
    for (int y = 0; y < 16; ++y) s += bl[x * 16 + y] * qv[y];
    kq[t * 16 + x] = 0.5f * s;  // fold (alpha-1)=0.5 here
  }
}

// ---------------- per-b: sc, entmax15, aw, arm ----------------
__global__ __launch_bounds__(256, 2) void k_attn(
    const float* __restrict__ xe_g, const float* __restrict__ kq_g,
    const float* __restrict__ eba, const float* __restrict__ ebb,
    const float* __restrict__ vals, bf16* __restrict__ arm) {
  __shared__ __align__(16) float s_xe[64 * 16];
  __shared__ float s_sum[16];
  __shared__ __align__(16) bf16 s_aw[256 * 72];  // [ko][f] padded
  __shared__ __align__(16) bf16 s_X[16 * 72];    // [e][f]  padded  (B-operand)
  const int t = threadIdx.x;
  const int b = blockIdx.x;
  const f32x2 z2 = {0.f, 0.f};

  ((float4*)s_xe)[t] = ((const float4*)(xe_g + (size_t)b * 1024))[t];
  __syncthreads();

  if (t < 16) {
    float s = 0.f;
#pragma unroll
    for (int f = 0; f < 64; ++f) s += s_xe[f * 16 + t];
    s_sum[t] = s;
  }
  {  // x_exp staging: 4 elements per thread, transposed [e][f]
    int f = t >> 2, e0 = (t & 3) * 4;
    float a = eba[f], c = ebb[f];
#pragma unroll
    for (int j = 0; j < 4; ++j) {
      float v = __expf(s_xe[f * 16 + e0 + j]) * a + c;
      s_X[(e0 + j) * 72 + f] = (bf16)v;
    }
  }
  __syncthreads();

  // ---- per-thread: ko = t ----
  f32x2 kq2[8];
  {
    const f32x4* g4 = (const f32x4*)(kq_g + t * 16);
#pragma unroll
    for (int j = 0; j < 4; ++j) {
      f32x4 v = g4[j];
      kq2[2 * j] = __builtin_shufflevector(v, v, 0, 1);
      kq2[2 * j + 1] = __builtin_shufflevector(v, v, 2, 3);
    }
  }
  float gc;
  {
    const f32x2* ss = (const f32x2*)s_sum;
    f32x2 g2 = z2;
#pragma unroll
    for (int i = 0; i < 8; ++i) g2 += ss[i] * kq2[i];
    gc = g2.x + g2.y;
  }

  f32x2 xs2[32];
#pragma unroll
  for (int f = 0; f < 64; ++f) {
    const f32x4* xr = (const f32x4*)(s_xe + f * 16);
    f32x4 A0 = xr[0], A1 = xr[1], A2 = xr[2], A3 = xr[3];
    f32x2 acc = z2;
    acc += __builtin_shufflevector(A0, A0, 0, 1) * kq2[0];
    acc += __builtin_shufflevector(A0, A0, 2, 3) * kq2[1];
    acc += __builtin_shufflevector(A1, A1, 0, 1) * kq2[2];
    acc += __builtin_shufflevector(A1, A1, 2, 3) * kq2[3];
    acc += __builtin_shufflevector(A2, A2, 0, 1) * kq2[4];
    acc += __builtin_shufflevector(A2, A2, 2, 3) * kq2[5];
    acc += __builtin_shufflevector(A3, A3, 0, 1) * kq2[6];
    acc += __builtin_shufflevector(A3, A3, 2, 3) * kq2[7];
    float v = (acc.x + acc.y) + gc;  // already scaled by 0.5 via kq
    if (f & 1) xs2[f >> 1].y = v; else xs2[f >> 1].x = v;
  }

  f32x2 m2 = xs2[0];
#pragma unroll
  for (int i = 1; i < 32; ++i) m2 = __builtin_elementwise_max(m2, xs2[i]);
  float mx = fmaxf(m2.x, m2.y);

  // bisection: f_lo >= 0 always (max element contributes exactly 1 at tau_lo)
  float tau_lo = mx - 1.0f;
  float dm = 0.875f;  // tau_hi - tau_lo = 1 - (1/64)^0.5
#pragma unroll
  for (int it = 0; it < 7; ++it) {
    dm *= 0.5f;
    float tm = tau_lo + dm;
    f32x2 t2 = {tm, tm};
    f32x2 c2 = z2;
#pragma unroll
    for (int i = 0; i < 32; ++i) {
      f32x2 d = xs2[i] - t2;
      d = __builtin_elementwise_max(d, z2);
      c2 += d * d;
    }
    tau_lo = ((c2.x + c2.y) - 1.0f >= 0.f) ? tm : tau_lo;
  }
  // two closed-form support solves from the right bracket end
  float tau = tau_lo + dm;
#pragma unroll
  for (int r = 0; r < 2; ++r) {
    f32x2 t2 = {tau, tau};
    f32x2 S2 = z2, Q2 = z2;
    float cnt = 0.f;
#pragma unroll
    for (int i = 0; i < 32; ++i) {
      f32x2 y = xs2[i] - t2;
      f32x2 m = __builtin_elementwise_max(y, z2);
      S2 += m; Q2 += m * m;
      cnt += (y.x > 0.f ? 1.f : 0.f) + (y.y > 0.f ? 1.f : 0.f);
    }
    float S1 = S2.x + S2.y, Q1 = Q2.x + Q2.y;
    float disc = fmaxf(S1 * S1 - cnt * (Q1 - 1.0f), 0.f);
    tau += (S1 - sqrtf(disc)) / cnt;
  }
  f32x2 Zv = z2;
  {
    f32x2 t2 = {tau, tau};
#pragma unroll
    for (int i = 0; i < 32; ++i) {
      f32x2 d = __builtin_elementwise_max(xs2[i] - t2, z2);
      f32x2 p = d * d;
      xs2[i] = p;
      Zv += p;
    }
  }
  float inv = 1.0f / (Zv.x + Zv.y);

  // aw[ko][f] = (p/Z) * vals[ko][f]  -> bf16 into A-operand layout
  const float4* vg = (const float4*)(vals + t * 64);
#pragma unroll
  for (int f8 = 0; f8 < 64; f8 += 8) {
    float4 v0 = vg[f8 / 4], v1 = vg[f8 / 4 + 1];
    union { bf16 h[8]; uint4 u; } pk;
    pk.h[0] = (bf16)(xs2[f8 / 2].x * inv * v0.x);
    pk.h[1] = (bf16)(xs2[f8 / 2].y * inv * v0.y);
    pk.h[2] = (bf16)(xs2[f8 / 2 + 1].x * inv * v0.z);
    pk.h[3] = (bf16)(xs2[f8 / 2 + 1].y * inv * v0.w);
    pk.h[4] = (bf16)(xs2[f8 / 2 + 2].x * inv * v1.x);
    pk.h[5] = (bf16)(xs2[f8 / 2 + 2].y * inv * v1.y);
    pk.h[6] = (bf16)(xs2[f8 / 2 + 3].x * inv * v1.z);
    pk.h[7] = (bf16)(xs2[f8 / 2 + 3].y * inv * v1.w);
    *(uint4*)(s_aw + t * 72 + f8) = pk.u;
  }
  __syncthreads();

  // arm[ko][e] = sum_f aw[ko][f] * x_exp[f][e]  via MFMA, M=256,N=16,K=64
  const int w = t >> 6, lane = t & 63;
  f32x4 acc[4];
#pragma unroll
  for (int mt = 0; mt < 4; ++mt) acc[mt] = (f32x4){0.f, 0.f, 0.f, 0.f};
#pragma unroll
  for (int ks = 0; ks < 2; ++ks) {
    bf16x8 bfrag = *(const bf16x8*)(s_X + (lane & 15) * 72 + ks * 32 + (lane >> 4) * 8);
#pragma unroll
    for (int mt = 0; mt < 4; ++mt) {
      int row = (w * 4 + mt) * 16 + (lane & 15);
      bf16x8 afrag = *(const bf16x8*)(s_aw + row * 72 + ks * 32 + (lane >> 4) * 8);
      acc[mt] = mfma_bf16(afrag, bfrag, acc[mt]);
    }
  }
  bf16* armb = arm + (size_t)b * 4096;
#pragma unroll
  for (int mt = 0; mt < 4; ++mt) {
    int ko0 = (w * 4 + mt) * 16 + (lane >> 4) * 4;
#pragma unroll
    for (int r = 0; r < 4; ++r)
      armb[(ko0 + r) * 16 + (lane & 15)] = (bf16)acc[mt][r];
  }
}

// ---------------- arm BN stats, coalesced + atomic ----------------
// grid 256, each block covers 16 b; thread t -> channel ko=t (16 e's contiguous)
__global__ void k_armstats(const bf16* __restrict__ arm, float* __restrict__ as_,
                           float* __restrict__ aq) {
  int t = threadIdx.x;
  int b0 = blockIdx.x * 16;
  float s = 0.f, q = 0.f;
  for (int i = 0; i < 16; ++i) {
    const bf16* p = arm + (size_t)(b0 + i) * 4096 + t * 16;
    bf16x8 v0 = *(const bf16x8*)p;
    bf16x8 v1 = *(const bf16x8*)(p + 8);
#pragma unroll
    for (int j = 0; j < 8; ++j) {
      float a = (float)v0[j], c = (float)v1[j];
      s += a + c; q += a * a + c * c;
    }
  }
  atomicAdd(as_ + t, s);
  atomicAdd(aq + t, q);
}

__global__ void k_armfin(const float* __restrict__ as_, const float* __restrict__ aq,
                         const float* __restrict__ g_, const float* __restrict__ b_,
                         float* __restrict__ oa, float* __restrict__ oc) {
  int ko = threadIdx.x;  // 256
  float mean = as_[ko] * (1.0f / 65536.0f);
  float var = aq[ko] * (1.0f / 65536.0f) - mean * mean;
  float a = g_[ko] * rsqrtf(var + EPS);
  oa[ko] = a;
  oc[ko] = b_[ko] - mean * a;
}

// ---------------- w1 convert with fused arm-BN column scale ----------------
__global__ void k_cvtw1s(const float* __restrict__ s, const float* __restrict__ a,
                         bf16* __restrict__ d, int n4) {
  int stride = gridDim.x * 256;
  for (int i = blockIdx.x * 256 + threadIdx.x; i < n4; i += stride) {
    float4 v = ((const float4*)s)[i];
    float av = a[(i >> 2) & 255];  // col j0 = (i*4)&4095, ko = j0>>4
    union { bf16 h[4]; uint2 u; } p;
    p.h[0] = (bf16)(v.x * av); p.h[1] = (bf16)(v.y * av);
    p.h[2] = (bf16)(v.z * av); p.h[3] = (bf16)(v.w * av);
    *(uint2*)(d + (size_t)i * 4) = p.u;
  }
}

// ---------------- bias1[h] = b1[h] + sum_j c[j>>4]*w1[h][j] ----------------
__global__ void k_bias1(const float* __restrict__ w1, const float* __restrict__ c,
                        const float* __restrict__ b1, float* __restrict__ bias1) {
  int t = threadIdx.x;
  int w = t >> 6, lane = t & 63;
  int h = blockIdx.x * 4 + w;
  const float4* row = (const float4*)(w1 + (size_t)h * 4096);
  float s = 0.f;
#pragma unroll
  for (int it = 0; it < 16; ++it) {
    int j4 = it * 64 + lane;
    float4 v = row[j4];
    float cj = c[j4 >> 2];
    s += cj * ((v.x + v.y) + (v.z + v.w));
  }
#pragma unroll
  for (int off = 32; off > 0; off >>= 1) s += __shfl_xor(s, off, 64);
  if (lane == 0) bias1[h] = b1[h] + s;
}

// ---------------- fp32 -> bf16 convert ----------------
__global__ void k_cvt(const float* __restrict__ s, bf16* __restrict__ d, int n4) {
  int stride = gridDim.x * 256;
  for (int i = blockIdx.x * 256 + threadIdx.x; i < n4; i += stride) {
    float4 v = ((const float4*)s)[i];
    union { bf16 h[4]; uint2 u; } p;
    p.h[0] = (bf16)v.x; p.h[1] = (bf16)v.y; p.h[2] = (bf16)v.z; p.h[3] = (bf16)v.w;
    *(uint2*)(d + (size_t)i * 4) = p.u;
  }
}

// ---------------- bf16 NT GEMM 128x64xBK32, + bias, + column stats ----------------
__global__ __launch_bounds__(256, 2) void gemm_bt(
    const bf16* __restrict__ A, const bf16* __restrict__ Bw,
    const float* __restrict__ bias, float* __restrict__ C,
    float* __restrict__ csum, float* __restrict__ csq, int Kd) {
  __shared__ __align__(16) bf16 sA[128 * 32];
  __shared__ __align__(16) bf16 sB[64 * 32];
  const int t = threadIdx.x;
  const int w = t >> 6, lane = t & 63;
  const int m0 = blockIdx.x * 128, n0 = blockIdx.y * 64;

  f32x4 acc[2][4];
#pragma unroll
  for (int i = 0; i < 2; ++i)
#pragma unroll
    for (int j = 0; j < 4; ++j) acc[i][j] = (f32x4){0.f, 0.f, 0.f, 0.f};

  for (int kt = 0; kt < Kd; kt += 32) {
#pragma unroll
    for (int c = 0; c < 2; ++c) {
      int idx = c * 256 + t;
      int row = idx >> 2, ch = idx & 3;
      int sch = ch ^ ((row >> 1) & 3);  // XOR swizzle to break ds_read bank conflicts
      lds_cp16(sA + idx * 8, A + (size_t)(m0 + row) * Kd + kt + sch * 8);
    }
    {
      int row = t >> 2, ch = t & 3;
      int sch = ch ^ ((row >> 1) & 3);
      lds_cp16(sB + t * 8, Bw + (size_t)(n0 + row) * Kd + kt + sch * 8);
    }
    __syncthreads();
    bf16x8 af[2], bfr[4];
#pragma unroll
    for (int mt = 0; mt < 2; ++mt) {
      int row = w * 32 + mt * 16 + (lane & 15);
      int ch = (lane >> 4) ^ ((row >> 1) & 3);
      af[mt] = *(const bf16x8*)(sA + row * 32 + ch * 8);
    }
#pragma unroll
    for (int nt = 0; nt < 4; ++nt) {
      int row = nt * 16 + (lane & 15);
      int ch = (lane >> 4) ^ ((row >> 1) & 3);
      bfr[nt] = *(const bf16x8*)(sB + row * 32 + ch * 8);
    }
#pragma unroll
    for (int mt = 0; mt < 2; ++mt)
#pragma unroll
      for (int nt = 0; nt < 4; ++nt)
        acc[mt][nt] = mfma_bf16(af[mt], bfr[nt], acc[mt][nt]);
    __syncthreads();
  }

#pragma unroll
  for (int nt = 0; nt < 4; ++nt) {
    int ncol = n0 + nt * 16 + (lane & 15);
    float bv = bias[ncol];
    float s = 0.f, q = 0.f;
#pragma unroll
    for (int mt = 0; mt < 2; ++mt) {
      int mr = m0 + w * 32 + mt * 16 + (lane >> 4) * 4;
#pragma unroll
      for (int r = 0; r < 4; ++r) {
        float v = acc[mt][nt][r] + bv;
        C[(size_t)(mr + r) * 1024 + ncol] = v;
        s += v; q += v * v;
      }
    }
    s += __shfl_xor(s, 16, 64); s += __shfl_xor(s, 32, 64);
    q += __shfl_xor(q, 16, 64); q += __shfl_xor(q, 32, 64);
    if ((lane >> 4) == 0) {
      atomicAdd(csum + ncol, s);
      atomicAdd(csq + ncol, q);
    }
  }
}

// ---------------- finalize per-column BN coefficients ----------------
__global__ void k_colfin(const float* __restrict__ s, const float* __restrict__ q,
                         const float* __restrict__ g_, const float* __restrict__ bt,
                         float* __restrict__ a, float* __restrict__ c) {
  int h = blockIdx.x * 256 + threadIdx.x;  // < 1024
  float mean = s[h] * (1.0f / 4096.0f);
  float var = q[h] * (1.0f / 4096.0f) - mean * mean;
  float av = g_[h] * rsqrtf(var + EPS);
  a[h] = av;
  c[h] = bt[h] - mean * av;
}

// ---------------- h1 = relu(bn(C1)) -> bf16 ----------------
__global__ void k_h1bf(const float* __restrict__ C1, const float* __restrict__ a,
                       const float* __restrict__ c, bf16* __restrict__ H1) {
  int i4 = blockIdx.x * 256 + threadIdx.x;  // over 1048576
  int col0 = (i4 * 4) & 1023;
  float4 v = ((const float4*)C1)[i4];
  float4 av = *(const float4*)(a + col0);
  float4 cv = *(const float4*)(c + col0);
  union { bf16 h[4]; uint2 u; } pk;
  pk.h[0] = (bf16)fmaxf(v.x * av.x + cv.x, 0.f);
  pk.h[1] = (bf16)fmaxf(v.y * av.y + cv.y, 0.f);
  pk.h[2] = (bf16)fmaxf(v.z * av.z + cv.z, 0.f);
  pk.h[3] = (bf16)fmaxf(v.w * av.w + cv.w, 0.f);
  *(uint2*)(H1 + (size_t)i4 * 4) = pk.u;
}

// ---------------- y[b] = sum_h relu(bn(C2)) * wout + bout ----------------
__global__ __launch_bounds__(256) void k_out(const float* __restrict__ C2,
                                             const float* __restrict__ a,
                                             const float* __restrict__ c,
                                             const float* __restrict__ wout,
                                             const float* __restrict__ bout,
                                             float* __restrict__ y) {
  int t = threadIdx.x;
  int w = t >> 6, lane = t & 63;
  int row = blockIdx.x * 4 + w;
  const float* cr = C2 + (size_t)row * 1024;
  float s = 0.f;
#pragma unroll
  for (int j = 0; j < 16; ++j) {
    int col = j * 64 + lane;
    float v = fmaxf(cr[col] * a[col] + c[col], 0.f);
    s += v * wout[col];
  }
#pragma unroll
  for (int off = 32; off > 0; off >>= 1) s += __shfl_xor(s, off, 64);
  if (lane == 0) y[row] = s + bout[0];
}

extern "C" void kernel_launch(void* const* d_in, const int* in_sizes, int n_in,
                              void* d_out, int out_size, void* d_ws, size_t ws_size,
                              hipStream_t stream) {
  (void)in_sizes; (void)n_in; (void)out_size; (void)ws_size;
  const int* x_id = (const int*)d_in[0];
  const float* x_value = (const float*)d_in[1];
  const float* emb = (const float*)d_in[2];
  const float* emb_g = (const float*)d_in[3];
  const float* embb = (const float*)d_in[4];
  const float* Qw = (const float*)d_in[5];
  const float* bil = (const float*)d_in[6];
  const float* vals = (const float*)d_in[7];
  const float* arm_g = (const float*)d_in[8];
  const float* arm_b = (const float*)d_in[9];
  const float* w1 = (const float*)d_in[10];
  const float* b1 = (const float*)d_in[11];
  const float* g1 = (const float*)d_in[12];
  const float* bt1 = (const float*)d_in[13];
  const float* w2 = (const float*)d_in[14];
  const float* b2 = (const float*)d_in[15];
  const float* g2 = (const float*)d_in[16];
  const float* bt2 = (const float*)d_in[17];
  const float* wout = (const float*)d_in[18];
  const float* bout = (const float*)d_in[19];

  char* w = (char*)d_ws;
  float* ws_xe = (float*)w;                 // 16 MB: xe, later C1, later C2
  float* ws_C = ws_xe;
  bf16* ws_arm = (bf16*)(w + 16777216);     // 32 MB: arm (bf16, raw; BN folded into W1)
  bf16* ws_H1 = (bf16*)(w + 50331648);      // 8 MB
  bf16* ws_w1b = (bf16*)(w + 58720256);     // 8 MB
  bf16* ws_w2b = (bf16*)(w + 67108864);     // 2 MB
  float* ws_kq = (float*)(w + 69206016);    // 16 KB
  float* st = (float*)(w + 69222400);       // stats region
  // zeroed block [0,5120):
  float* es = st;            // 64
  float* eq = es + 64;       // 64
  float* as_ = eq + 64;      // 256
  float* aq = as_ + 256;     // 256
  float* s1 = aq + 256;      // 1024
  float* q1 = s1 + 1024;
  float* s2 = q1 + 1024;
  float* q2 = s2 + 1024;     // ends 4736; pad to 5120
  // non-zeroed:
  float* eb_a = st + 5120;   // 64
  float* eb_b = eb_a + 64;
  float* arm_a = eb_b + 64;  // 256
  float* arm_c = arm_a + 256;
  float* a1c = arm_c + 256;  // 1024
  float* c1c = a1c + 1024;
  float* a2c = c1c + 1024;
  float* c2c = a2c + 1024;
  float* bias1 = c2c + 1024;

  k_zero<<<20, 256, 0, stream>>>(st);
  k_embed<<<1024, 256, 0, stream>>>(x_id, x_value, emb, ws_xe);
  k_expstats<<<256, 256, 0, stream>>>(ws_xe, es, eq);
  k_expfin<<<1, 64, 0, stream>>>(es, eq, emb_g, embb, eb_a, eb_b);
  k_kq<<<1, 256, 0, stream>>>(Qw, bil, ws_kq);
  k_attn<<<4096, 256, 0, stream>>>(ws_xe, ws_kq, eb_a, eb_b, vals, ws_arm);
  k_armstats<<<256, 256, 0, stream>>>(ws_arm, as_, aq);
  k_armfin<<<1, 256, 0, stream>>>(as_, aq, arm_g, arm_b, arm_a, arm_c);
  k_cvtw1s<<<1024, 256, 0, stream>>>(w1, arm_a, ws_w1b, 1048576);
  k_bias1<<<256, 256, 0, stream>>>(w1, arm_c, b1, bias1);
  k_cvt<<<256, 256, 0, stream>>>(w2, ws_w2b, 262144);
  gemm_bt<<<dim3(32, 16), 256, 0, stream>>>(ws_arm, ws_w1b, bias1, ws_C, s1, q1, 4096);
  k_colfin<<<4, 256, 0, stream>>>(s1, q1, g1, bt1, a1c, c1c);
  k_h1bf<<<4096, 256, 0, stream>>>(ws_C, a1c, c1c, ws_H1);
  gemm_bt<<<dim3(32, 16), 256, 0, stream>>>(ws_H1, ws_w2b, b2, ws_C, s2, q2, 1024);
  k_colfin<<<4, 256, 0, stream>>>(s2, q2, g2, bt2, a2c, c2c);
  k_out<<<1024, 256, 0, stream>>>(ws_C, a2c, c2c, wout, bout, (float*)d_out);
}